// Round 5
// baseline (288.206 us; speedup 1.0000x reference)
//
#include <hip/hip_runtime.h>
#include <hip/hip_bf16.h>

typedef short s16x8 __attribute__((ext_vector_type(8)));
typedef float f32x4 __attribute__((ext_vector_type(4)));
typedef unsigned short u16x8 __attribute__((ext_vector_type(8)));

static constexpr int Bc   = 8;
static constexpr int Nn   = 24576;
static constexpr int Kk   = 16;
static constexpr int Cc   = 64;
static constexpr int Rr   = Bc * Nn;     // 196608
static constexpr float EPS = 1e-5f;

__device__ __forceinline__ unsigned short f2bf(float f) {
    union { float f; unsigned int u; } c; c.f = f;
    unsigned int r = c.u + 0x7FFFu + ((c.u >> 16) & 1u);  // RNE
    return (unsigned short)(r >> 16);
}
__device__ __forceinline__ float bf2f(unsigned short u) {
    union { unsigned int u; float f; } c; c.u = ((unsigned int)u) << 16; return c.f;
}

// ---------------------------------------------------------------------------
// K1: h = x · W^T via MFMA (bf16 in, fp32 acc, bf16 out).
// Per wave: one 16-row x 64-col tile = 4 col-tiles x 2 k-chunks = 8 MFMA.
// A frag: lane l holds x[row0+(l&15)][(l>>4)*8 + kc*32 + j], j=0..7 (16B load).
// B frag: lane l holds W[ct*16+(l&15)][(l>>4)*8 + kc*32 + j]  (same pattern).
// D: col = l&15, row = (l>>4)*4 + reg   [verified layout, m89/m91].
// ---------------------------------------------------------------------------
__global__ __launch_bounds__(256) void linear_mfma_kernel(
    const float* __restrict__ x, const float* __restrict__ W,
    __hip_bfloat16* __restrict__ h)
{
    const int tid  = threadIdx.x;
    const int l    = tid & 63;
    const int wave = tid >> 6;
    const int gwave = blockIdx.x * 4 + wave;
    const int nwav  = gridDim.x * 4;

    const int lr = l & 15;
    const int kg = (l >> 4) * 8;
    const int dr = (l >> 4) * 4;

    // B fragments (W is 16 KB, L2-hot): 4 col-tiles x 2 k-chunks
    s16x8 bfrag[4][2];
#pragma unroll
    for (int ct = 0; ct < 4; ++ct)
#pragma unroll
        for (int kc = 0; kc < 2; ++kc) {
            const float* bp = W + (ct * 16 + lr) * 64 + kc * 32 + kg;
            f32x4 b0 = *reinterpret_cast<const f32x4*>(bp);
            f32x4 b1 = *reinterpret_cast<const f32x4*>(bp + 4);
            s16x8 f;
            f[0] = (short)f2bf(b0[0]); f[1] = (short)f2bf(b0[1]);
            f[2] = (short)f2bf(b0[2]); f[3] = (short)f2bf(b0[3]);
            f[4] = (short)f2bf(b1[0]); f[5] = (short)f2bf(b1[1]);
            f[6] = (short)f2bf(b1[2]); f[7] = (short)f2bf(b1[3]);
            bfrag[ct][kc] = f;
        }

    unsigned short* hu = (unsigned short*)h;
    const int ntiles = Rr / 16;  // 12288
    for (int t = gwave; t < ntiles; t += nwav) {
        const int row0 = t * 16;
        const float* ap = x + (row0 + lr) * 64 + kg;
        f32x4 a0 = *reinterpret_cast<const f32x4*>(ap);
        f32x4 a1 = *reinterpret_cast<const f32x4*>(ap + 4);
        f32x4 a2 = *reinterpret_cast<const f32x4*>(ap + 32);
        f32x4 a3 = *reinterpret_cast<const f32x4*>(ap + 36);
        s16x8 fa0, fa1;
        fa0[0] = (short)f2bf(a0[0]); fa0[1] = (short)f2bf(a0[1]);
        fa0[2] = (short)f2bf(a0[2]); fa0[3] = (short)f2bf(a0[3]);
        fa0[4] = (short)f2bf(a1[0]); fa0[5] = (short)f2bf(a1[1]);
        fa0[6] = (short)f2bf(a1[2]); fa0[7] = (short)f2bf(a1[3]);
        fa1[0] = (short)f2bf(a2[0]); fa1[1] = (short)f2bf(a2[1]);
        fa1[2] = (short)f2bf(a2[2]); fa1[3] = (short)f2bf(a2[3]);
        fa1[4] = (short)f2bf(a3[0]); fa1[5] = (short)f2bf(a3[1]);
        fa1[6] = (short)f2bf(a3[2]); fa1[7] = (short)f2bf(a3[3]);

        f32x4 acc[4];
#pragma unroll
        for (int ct = 0; ct < 4; ++ct) { acc[ct] = (f32x4){0.f, 0.f, 0.f, 0.f}; }
#pragma unroll
        for (int ct = 0; ct < 4; ++ct) {
            acc[ct] = __builtin_amdgcn_mfma_f32_16x16x32_bf16(fa0, bfrag[ct][0], acc[ct], 0, 0, 0);
            acc[ct] = __builtin_amdgcn_mfma_f32_16x16x32_bf16(fa1, bfrag[ct][1], acc[ct], 0, 0, 0);
        }
#pragma unroll
        for (int ct = 0; ct < 4; ++ct)
#pragma unroll
            for (int r = 0; r < 4; ++r)
                hu[(row0 + dr + r) * 64 + ct * 16 + lr] = f2bf(acc[ct][r]);
    }
}

// ---------------------------------------------------------------------------
// K2: v[r][o] = (max_k h[nbr(r,k)][o]) - h[r][o], v stored bf16 (nt store).
// 2 rows per wave-iteration -> 32 gathers in flight. knn via nt load, v via
// nt store so the 3 MB/batch h slice stays L2-resident. Stats in fp32.
// ---------------------------------------------------------------------------
__global__ __launch_bounds__(256, 6) void gather_bn_kernel(
    const __hip_bfloat16* __restrict__ h, const int* __restrict__ knn,
    __hip_bfloat16* __restrict__ v, float* __restrict__ stats)
{
    const int tid   = threadIdx.x;
    const int lane  = tid & 63;
    const int wave  = tid >> 6;
    const int gwave = blockIdx.x * 4 + wave;
    const int nwav  = gridDim.x * 4;   // 8192

    const unsigned short* hu = (const unsigned short*)h;
    unsigned short* vu = (unsigned short*)v;

    float lsum = 0.f, lsq = 0.f;

    for (int r0 = gwave * 2; r0 < Rr; r0 += nwav * 2) {
        const int row0 = r0, row1 = r0 + 1;          // row0 even -> same batch
        const int bbase = (row0 / Nn) * Nn;
        const int i0 = __builtin_nontemporal_load(&knn[row0 * Kk + (lane & 15)]);
        const int i1 = __builtin_nontemporal_load(&knn[row1 * Kk + (lane & 15)]);
        const float o0 = bf2f(hu[row0 * 64 + lane]);
        const float o1 = bf2f(hu[row1 * 64 + lane]);
        float m0 = -3e38f, m1 = -3e38f;
#pragma unroll
        for (int k = 0; k < Kk; ++k) {
            const int j0 = __shfl(i0, k);
            const int j1 = __shfl(i1, k);
            const float g0 = bf2f(hu[(bbase + j0) * 64 + lane]);
            const float g1 = bf2f(hu[(bbase + j1) * 64 + lane]);
            m0 = fmaxf(m0, g0);
            m1 = fmaxf(m1, g1);
        }
        const float v0 = m0 - o0, v1 = m1 - o1;
        __builtin_nontemporal_store(f2bf(v0), &vu[row0 * 64 + lane]);
        __builtin_nontemporal_store(f2bf(v1), &vu[row1 * 64 + lane]);
        lsum += v0 + v1;
        lsq  += v0 * v0 + v1 * v1;
    }

    __shared__ float s_sum[4][64];
    __shared__ float s_sq[4][64];
    s_sum[wave][lane] = lsum;
    s_sq[wave][lane]  = lsq;
    __syncthreads();
    if (wave == 0) {
        const float a = s_sum[0][lane] + s_sum[1][lane] + s_sum[2][lane] + s_sum[3][lane];
        const float q = s_sq[0][lane]  + s_sq[1][lane]  + s_sq[2][lane]  + s_sq[3][lane];
        atomicAdd(&stats[lane], a);
        atomicAdd(&stats[64 + lane], q);
    }
}

// ---------------------------------------------------------------------------
// K3: finalize BN stats -> scale/shift (one 64-thread block)
// ---------------------------------------------------------------------------
__global__ __launch_bounds__(64) void finalize_stats_kernel(
    const float* __restrict__ stats, const float* __restrict__ gamma,
    const float* __restrict__ beta, float* __restrict__ ss)
{
    const int o = threadIdx.x;
    const float inv_count = 1.0f / (float)Rr;
    const float mean = stats[o] * inv_count;
    const float var  = stats[64 + o] * inv_count - mean * mean;
    const float sc   = gamma[o] * rsqrtf(var + EPS);
    ss[o]      = sc;
    ss[64 + o] = beta[o] - mean * sc;
}

// ---------------------------------------------------------------------------
// K4: out = v_bf16 * scale[c] + shift[c]; nt streams, 8 elems/thread.
// ---------------------------------------------------------------------------
__global__ __launch_bounds__(256) void norm_kernel(
    const __hip_bfloat16* __restrict__ v, const float* __restrict__ ss,
    float* __restrict__ out)
{
    __shared__ float sc[64], sh[64];
    if (threadIdx.x < 64) {
        sc[threadIdx.x] = ss[threadIdx.x];
        sh[threadIdx.x] = ss[64 + threadIdx.x];
    }
    __syncthreads();

    const u16x8* vu = (const u16x8*)v;
    const int total8 = Rr * 64 / 8;  // 1,572,864
    for (int i = blockIdx.x * blockDim.x + threadIdx.x; i < total8;
         i += gridDim.x * blockDim.x) {
        u16x8 t = __builtin_nontemporal_load(&vu[i]);
        const int c = (i * 8) & 63;
        f32x4 r0, r1;
        r0[0] = bf2f(t[0]) * sc[c + 0] + sh[c + 0];
        r0[1] = bf2f(t[1]) * sc[c + 1] + sh[c + 1];
        r0[2] = bf2f(t[2]) * sc[c + 2] + sh[c + 2];
        r0[3] = bf2f(t[3]) * sc[c + 3] + sh[c + 3];
        r1[0] = bf2f(t[4]) * sc[c + 4] + sh[c + 4];
        r1[1] = bf2f(t[5]) * sc[c + 5] + sh[c + 5];
        r1[2] = bf2f(t[6]) * sc[c + 6] + sh[c + 6];
        r1[3] = bf2f(t[7]) * sc[c + 7] + sh[c + 7];
        f32x4* op = reinterpret_cast<f32x4*>(out + (size_t)i * 8);
        __builtin_nontemporal_store(r0, op);
        __builtin_nontemporal_store(r1, op + 1);
    }
}

// ---------------------------------------------------------------------------
extern "C" void kernel_launch(void* const* d_in, const int* in_sizes, int n_in,
                              void* d_out, int out_size, void* d_ws, size_t ws_size,
                              hipStream_t stream)
{
    const float* x     = (const float*)d_in[0];
    const float* W     = (const float*)d_in[1];
    const float* gamma = (const float*)d_in[2];
    const float* beta  = (const float*)d_in[3];
    const int*   knn   = (const int*)d_in[4];
    float*       out   = (float*)d_out;

    // ws layout: h bf16 [Rr*64] | v bf16 [Rr*64] | stats[128] | ss[128]
    __hip_bfloat16* h = (__hip_bfloat16*)d_ws;
    __hip_bfloat16* v = h + (size_t)Rr * 64;
    float* stats = (float*)((char*)d_ws + 2 * (size_t)Rr * 64 * sizeof(__hip_bfloat16));
    float* ss    = stats + 128;

    (void)hipMemsetAsync(stats, 0, 128 * sizeof(float), stream);

    linear_mfma_kernel<<<1024, 256, 0, stream>>>(x, W, h);
    gather_bn_kernel<<<2048, 256, 0, stream>>>(h, knn, v, stats);
    finalize_stats_kernel<<<1, 64, 0, stream>>>(stats, gamma, beta, ss);
    norm_kernel<<<2048, 256, 0, stream>>>(v, ss, out);
}

// Round 6
// 221.842 us; speedup vs baseline: 1.2992x; 1.2992x over previous
//
#include <hip/hip_runtime.h>
#include <hip/hip_bf16.h>

typedef short s16x8 __attribute__((ext_vector_type(8)));
typedef float f32x4 __attribute__((ext_vector_type(4)));
typedef unsigned short u16x8 __attribute__((ext_vector_type(8)));

static constexpr int Bc   = 8;
static constexpr int Nn   = 24576;
static constexpr int Kk   = 16;
static constexpr int Cc   = 64;
static constexpr int Rr   = Bc * Nn;     // 196608
static constexpr float EPS = 1e-5f;

__device__ __forceinline__ unsigned short f2bf(float f) {
    union { float f; unsigned int u; } c; c.f = f;
    unsigned int r = c.u + 0x7FFFu + ((c.u >> 16) & 1u);  // RNE
    return (unsigned short)(r >> 16);
}
__device__ __forceinline__ float bf2f(unsigned short u) {
    union { unsigned int u; float f; } c; c.u = ((unsigned int)u) << 16; return c.f;
}

// ---------------------------------------------------------------------------
// K1: h = x · W^T via MFMA (bf16 in, fp32 acc, bf16 out).
// XCD-batch partition: batch = bid%8 -> all of batch b's h is written through
// XCD b's L2 (write-allocate) and stays resident for K2.
// Per wave: one 16x64 tile = 4 col-tiles x 2 k-chunks = 8 MFMA.
// D layout: col = l&15, row = (l>>4)*4 + reg  [verified m89/m91].
// ---------------------------------------------------------------------------
__global__ __launch_bounds__(256) void linear_mfma_kernel(
    const float* __restrict__ x, const float* __restrict__ W,
    __hip_bfloat16* __restrict__ h)
{
    const int tid  = threadIdx.x;
    const int l    = tid & 63;
    const int wave = tid >> 6;
    const int batch = blockIdx.x & 7;          // -> XCD (round-robin dispatch)
    const int qb    = blockIdx.x >> 3;         // 0..255
    const int wib   = qb * 4 + wave;           // wave-in-batch 0..1023

    const int lr = l & 15;
    const int kg = (l >> 4) * 8;
    const int dr = (l >> 4) * 4;

    s16x8 bfrag[4][2];
#pragma unroll
    for (int ct = 0; ct < 4; ++ct)
#pragma unroll
        for (int kc = 0; kc < 2; ++kc) {
            const float* bp = W + (ct * 16 + lr) * 64 + kc * 32 + kg;
            f32x4 b0 = *reinterpret_cast<const f32x4*>(bp);
            f32x4 b1 = *reinterpret_cast<const f32x4*>(bp + 4);
            s16x8 f;
            f[0] = (short)f2bf(b0[0]); f[1] = (short)f2bf(b0[1]);
            f[2] = (short)f2bf(b0[2]); f[3] = (short)f2bf(b0[3]);
            f[4] = (short)f2bf(b1[0]); f[5] = (short)f2bf(b1[1]);
            f[6] = (short)f2bf(b1[2]); f[7] = (short)f2bf(b1[3]);
            bfrag[ct][kc] = f;
        }

    unsigned short* hu = (unsigned short*)h;
    const int tiles_per_batch = Nn / 16;       // 1536
    for (int t = wib; t < tiles_per_batch; t += 1024) {
        const int row0 = batch * Nn + t * 16;
        const float* ap = x + (size_t)(row0 + lr) * 64 + kg;
        f32x4 a0 = *reinterpret_cast<const f32x4*>(ap);
        f32x4 a1 = *reinterpret_cast<const f32x4*>(ap + 4);
        f32x4 a2 = *reinterpret_cast<const f32x4*>(ap + 32);
        f32x4 a3 = *reinterpret_cast<const f32x4*>(ap + 36);
        s16x8 fa0, fa1;
        fa0[0] = (short)f2bf(a0[0]); fa0[1] = (short)f2bf(a0[1]);
        fa0[2] = (short)f2bf(a0[2]); fa0[3] = (short)f2bf(a0[3]);
        fa0[4] = (short)f2bf(a1[0]); fa0[5] = (short)f2bf(a1[1]);
        fa0[6] = (short)f2bf(a1[2]); fa0[7] = (short)f2bf(a1[3]);
        fa1[0] = (short)f2bf(a2[0]); fa1[1] = (short)f2bf(a2[1]);
        fa1[2] = (short)f2bf(a2[2]); fa1[3] = (short)f2bf(a2[3]);
        fa1[4] = (short)f2bf(a3[0]); fa1[5] = (short)f2bf(a3[1]);
        fa1[6] = (short)f2bf(a3[2]); fa1[7] = (short)f2bf(a3[3]);

        f32x4 acc[4];
#pragma unroll
        for (int ct = 0; ct < 4; ++ct) { acc[ct] = (f32x4){0.f, 0.f, 0.f, 0.f}; }
#pragma unroll
        for (int ct = 0; ct < 4; ++ct) {
            acc[ct] = __builtin_amdgcn_mfma_f32_16x16x32_bf16(fa0, bfrag[ct][0], acc[ct], 0, 0, 0);
            acc[ct] = __builtin_amdgcn_mfma_f32_16x16x32_bf16(fa1, bfrag[ct][1], acc[ct], 0, 0, 0);
        }
#pragma unroll
        for (int ct = 0; ct < 4; ++ct)
#pragma unroll
            for (int r = 0; r < 4; ++r)
                hu[(size_t)(row0 + dr + r) * 64 + ct * 16 + lr] = f2bf(acc[ct][r]);
    }
}

// ---------------------------------------------------------------------------
// K2: v[r][o] = (max_k h[nbr(r,k)][o]) - h[r][o], v bf16.
// batch = bid%8 -> all gathers for batch b run on XCD b, whose L2 holds the
// 3 MB h slice (written there by K1). Normal loads/stores throughout.
// 2 rows per wave-iteration; per-wave 12 iterations.
// ---------------------------------------------------------------------------
__global__ __launch_bounds__(256) void gather_bn_kernel(
    const __hip_bfloat16* __restrict__ h, const int* __restrict__ knn,
    __hip_bfloat16* __restrict__ v, float* __restrict__ stats)
{
    const int tid   = threadIdx.x;
    const int lane  = tid & 63;
    const int wave  = tid >> 6;
    const int batch = blockIdx.x & 7;
    const int qb    = blockIdx.x >> 3;
    const int wib   = qb * 4 + wave;           // 0..1023

    const unsigned short* hu = (const unsigned short*)h;
    unsigned short* vu = (unsigned short*)v;
    const int bbase = batch * Nn;

    float lsum = 0.f, lsq = 0.f;

    for (int r = wib * 2; r < Nn; r += 2048) {
        const int row0 = bbase + r, row1 = row0 + 1;
        const int i0 = knn[(size_t)row0 * Kk + (lane & 15)];
        const int i1 = knn[(size_t)row1 * Kk + (lane & 15)];
        const float o0 = bf2f(hu[(size_t)row0 * 64 + lane]);
        const float o1 = bf2f(hu[(size_t)row1 * 64 + lane]);
        float m0 = -3e38f, m1 = -3e38f;
#pragma unroll
        for (int k = 0; k < Kk; ++k) {
            const int j0 = __shfl(i0, k);
            const int j1 = __shfl(i1, k);
            const float g0 = bf2f(hu[(size_t)(bbase + j0) * 64 + lane]);
            const float g1 = bf2f(hu[(size_t)(bbase + j1) * 64 + lane]);
            m0 = fmaxf(m0, g0);
            m1 = fmaxf(m1, g1);
        }
        const float v0 = m0 - o0, v1 = m1 - o1;
        vu[(size_t)row0 * 64 + lane] = f2bf(v0);
        vu[(size_t)row1 * 64 + lane] = f2bf(v1);
        lsum += v0 + v1;
        lsq  += v0 * v0 + v1 * v1;
    }

    __shared__ float s_sum[4][64];
    __shared__ float s_sq[4][64];
    s_sum[wave][lane] = lsum;
    s_sq[wave][lane]  = lsq;
    __syncthreads();
    if (wave == 0) {
        const float a = s_sum[0][lane] + s_sum[1][lane] + s_sum[2][lane] + s_sum[3][lane];
        const float q = s_sq[0][lane]  + s_sq[1][lane]  + s_sq[2][lane]  + s_sq[3][lane];
        atomicAdd(&stats[lane], a);
        atomicAdd(&stats[64 + lane], q);
    }
}

// ---------------------------------------------------------------------------
// K3: finalize BN stats -> scale/shift (one 64-thread block)
// ---------------------------------------------------------------------------
__global__ __launch_bounds__(64) void finalize_stats_kernel(
    const float* __restrict__ stats, const float* __restrict__ gamma,
    const float* __restrict__ beta, float* __restrict__ ss)
{
    const int o = threadIdx.x;
    const float inv_count = 1.0f / (float)Rr;
    const float mean = stats[o] * inv_count;
    const float var  = stats[64 + o] * inv_count - mean * mean;
    const float sc   = gamma[o] * rsqrtf(var + EPS);
    ss[o]      = sc;
    ss[64 + o] = beta[o] - mean * sc;
}

// ---------------------------------------------------------------------------
// K4: out = v_bf16 * scale[c] + shift[c]. Same batch partition so v is read
// from the XCD L2 that K2 wrote it through. nt only on the fp32 out stream.
// ---------------------------------------------------------------------------
__global__ __launch_bounds__(256) void norm_kernel(
    const __hip_bfloat16* __restrict__ v, const float* __restrict__ ss,
    float* __restrict__ out)
{
    __shared__ float sc[64], sh[64];
    if (threadIdx.x < 64) {
        sc[threadIdx.x] = ss[threadIdx.x];
        sh[threadIdx.x] = ss[64 + threadIdx.x];
    }
    __syncthreads();

    const int batch = blockIdx.x & 7;
    const int qb    = blockIdx.x >> 3;          // 0..255
    const u16x8* vu = (const u16x8*)v;
    const int per_batch8 = Nn * 64 / 8;         // 196608 float8-groups per batch
    const size_t base8 = (size_t)batch * per_batch8;

    for (int li = qb * 256 + threadIdx.x; li < per_batch8; li += 256 * 256) {
        const size_t i = base8 + li;
        u16x8 t = vu[i];
        const int c = (li * 8) & 63;
        f32x4 r0, r1;
        r0[0] = bf2f(t[0]) * sc[c + 0] + sh[c + 0];
        r0[1] = bf2f(t[1]) * sc[c + 1] + sh[c + 1];
        r0[2] = bf2f(t[2]) * sc[c + 2] + sh[c + 2];
        r0[3] = bf2f(t[3]) * sc[c + 3] + sh[c + 3];
        r1[0] = bf2f(t[4]) * sc[c + 4] + sh[c + 4];
        r1[1] = bf2f(t[5]) * sc[c + 5] + sh[c + 5];
        r1[2] = bf2f(t[6]) * sc[c + 6] + sh[c + 6];
        r1[3] = bf2f(t[7]) * sc[c + 7] + sh[c + 7];
        f32x4* op = reinterpret_cast<f32x4*>(out + i * 8);
        __builtin_nontemporal_store(r0, op);
        __builtin_nontemporal_store(r1, op + 1);
    }
}

// ---------------------------------------------------------------------------
extern "C" void kernel_launch(void* const* d_in, const int* in_sizes, int n_in,
                              void* d_out, int out_size, void* d_ws, size_t ws_size,
                              hipStream_t stream)
{
    const float* x     = (const float*)d_in[0];
    const float* W     = (const float*)d_in[1];
    const float* gamma = (const float*)d_in[2];
    const float* beta  = (const float*)d_in[3];
    const int*   knn   = (const int*)d_in[4];
    float*       out   = (float*)d_out;

    // ws layout: h bf16 [Rr*64] | v bf16 [Rr*64] | stats[128] | ss[128]
    __hip_bfloat16* h = (__hip_bfloat16*)d_ws;
    __hip_bfloat16* v = h + (size_t)Rr * 64;
    float* stats = (float*)((char*)d_ws + 2 * (size_t)Rr * 64 * sizeof(__hip_bfloat16));
    float* ss    = stats + 128;

    (void)hipMemsetAsync(stats, 0, 128 * sizeof(float), stream);

    linear_mfma_kernel<<<2048, 256, 0, stream>>>(x, W, h);
    gather_bn_kernel<<<2048, 256, 0, stream>>>(h, knn, v, stats);
    finalize_stats_kernel<<<1, 64, 0, stream>>>(stats, gamma, beta, ss);
    norm_kernel<<<2048, 256, 0, stream>>>(v, ss, out);
}